// Round 1
// baseline (245.956 us; speedup 1.0000x reference)
//
#include <hip/hip_runtime.h>
#include <stdint.h>

typedef unsigned short u16;
typedef __attribute__((ext_vector_type(8))) short short8;
typedef __attribute__((ext_vector_type(4))) float f32x4;

#define AS1C(p) ((const __attribute__((address_space(1))) void*)(p))
#define AS3(p)  ((__attribute__((address_space(3))) void*)(p))

__device__ __forceinline__ u16 to_bf16(float f) {
  unsigned u = __builtin_bit_cast(unsigned, f);
  u += 0x7FFFu + ((u >> 16) & 1u);
  return (u16)(u >> 16);
}

// ---------------------------------------------------------------------------
// x[b][c][n] fp32 -> xT[b][n][c] bf16   (B=16, C=512, N=1024)
__global__ __launch_bounds__(256) void xpose_cvt(const float* __restrict__ x,
                                                 u16* __restrict__ xT) {
  __shared__ float t[32][33];
  int b = blockIdx.z;
  int n0 = blockIdx.x * 32, c0 = blockIdx.y * 32;
  int tx = threadIdx.x & 31, ty = threadIdx.x >> 5;  // ty 0..7
  const float* xp = x + (size_t)b * 512 * 1024;
#pragma unroll
  for (int i = 0; i < 32; i += 8)
    t[ty + i][tx] = xp[(size_t)(c0 + ty + i) * 1024 + n0 + tx];
  __syncthreads();
  u16* op = xT + (size_t)b * 1024 * 512;
#pragma unroll
  for (int i = 0; i < 32; i += 8)
    op[(size_t)(n0 + ty + i) * 512 + c0 + tx] = to_bf16(t[tx][ty + i]);
}

__global__ __launch_bounds__(256) void cvt_bf16(const float* __restrict__ s,
                                                u16* __restrict__ d, int n) {
  int i = blockIdx.x * 256 + threadIdx.x;
  if (i < n) d[i] = to_bf16(s[i]);
}

// ---------------------------------------------------------------------------
// Generic 128x128-tile bf16 GEMM, K=512, BK=32, both operands row-major with
// 512-contiguous K (A rows = D rows, B rows = D cols). m97 structure:
// global_load_lds width 16, 2 barriers per K-step, 4 waves 2x2, 4x4 frags.
// MODE 0: A=xT[b] (rows n), B=qkv_w rows 0..1023 (cols o) -> Q/K [bh][n][64]
// MODE 1: A=qkv_w rows 1024.. (rows o'), B=xT[b] (cols n) -> V [bh][c][n]
// MODE 2: A=out_w (rows o), B=attnT[b] (cols n) -> fp32 out = g*(D+b)+x
template <int MODE>
__global__ __launch_bounds__(256) void gemm_bt(
    const u16* __restrict__ Abase, const u16* __restrict__ Bbase,
    long saB, long sbB,
    const float* __restrict__ bias, const float* __restrict__ xres,
    const float* __restrict__ gammap,
    u16* __restrict__ oq, u16* __restrict__ ok, u16* __restrict__ ov,
    float* __restrict__ of) {
  __shared__ __align__(16) u16 lsA[128 * 32];
  __shared__ __align__(16) u16 lsB[128 * 32];
  int b = blockIdx.z;
  const u16* Ag = Abase + (size_t)b * saB;
  const u16* Bg = Bbase + (size_t)b * sbB;
  int m0 = blockIdx.y * 128, n0 = blockIdx.x * 128;
  int tid = threadIdx.x;
  int w = tid >> 6, l = tid & 63;
  int wr = w >> 1, wc = w & 1;
  int lq = l >> 4, lr = l & 15;
  int rowA = w * 32 + (l >> 2);
  int k8 = (l & 3) * 8;
  f32x4 acc[4][4] = {};
  for (int kk = 0; kk < 16; ++kk) {
    int ko = kk * 32;
    __builtin_amdgcn_global_load_lds(
        AS1C(Ag + (size_t)(m0 + rowA) * 512 + ko + k8),
        AS3(&lsA[rowA * 32 + k8]), 16, 0, 0);
    __builtin_amdgcn_global_load_lds(
        AS1C(Ag + (size_t)(m0 + rowA + 16) * 512 + ko + k8),
        AS3(&lsA[(rowA + 16) * 32 + k8]), 16, 0, 0);
    __builtin_amdgcn_global_load_lds(
        AS1C(Bg + (size_t)(n0 + rowA) * 512 + ko + k8),
        AS3(&lsB[rowA * 32 + k8]), 16, 0, 0);
    __builtin_amdgcn_global_load_lds(
        AS1C(Bg + (size_t)(n0 + rowA + 16) * 512 + ko + k8),
        AS3(&lsB[(rowA + 16) * 32 + k8]), 16, 0, 0);
    __syncthreads();
    short8 af[4], bfr[4];
#pragma unroll
    for (int m = 0; m < 4; ++m)
      af[m] = *(const short8*)&lsA[(wr * 64 + m * 16 + lr) * 32 + lq * 8];
#pragma unroll
    for (int j = 0; j < 4; ++j)
      bfr[j] = *(const short8*)&lsB[(wc * 64 + j * 16 + lr) * 32 + lq * 8];
#pragma unroll
    for (int m = 0; m < 4; ++m)
#pragma unroll
      for (int j = 0; j < 4; ++j)
        acc[m][j] = __builtin_amdgcn_mfma_f32_16x16x32_bf16(af[m], bfr[j],
                                                            acc[m][j], 0, 0, 0);
    __syncthreads();
  }
  float g = (MODE == 2) ? gammap[0] : 0.f;
#pragma unroll
  for (int m = 0; m < 4; ++m)
#pragma unroll
    for (int j = 0; j < 4; ++j)
#pragma unroll
      for (int e = 0; e < 4; ++e) {
        int row = m0 + wr * 64 + m * 16 + lq * 4 + e;
        int col = n0 + wc * 64 + j * 16 + lr;
        float v = acc[m][j][e];
        if (MODE == 0) {
          int o = col, n = row;
          v += bias[o];
          int oo = (o < 512) ? o : o - 512;
          int hh = oo >> 6, cc = oo & 63;
          u16* dst = (o < 512) ? oq : ok;
          dst[((size_t)(b * 8 + hh) * 1024 + n) * 64 + cc] = to_bf16(v);
        } else if (MODE == 1) {
          int o = row, n = col;
          v += bias[o];  // bias pre-offset by +1024 on host side
          int hh = o >> 6, cc = o & 63;
          ov[((size_t)(b * 8 + hh) * 64 + cc) * 1024 + n] = to_bf16(v);
        } else {
          int o = row, n = col;
          v += bias[o];
          size_t idx = ((size_t)b * 512 + o) * 1024 + n;
          of[idx] = g * v + xres[idx];
        }
      }
}

// ---------------------------------------------------------------------------
// Flash attention: Q/K in [bh][n][64] bf16, V in [bh][c][n] bf16.
// Block = 4 waves x 32 Q-rows = 128 rows; KBLK = 64; online softmax.
// Output attnT[b][n][512] bf16 (c_global = h*64 + c).
#define CS 0.18033688f  // (1/sqrt(64)) * log2(e)

__global__ __launch_bounds__(256) void attn_fused(const u16* __restrict__ Qb,
                                                  const u16* __restrict__ Kb,
                                                  const u16* __restrict__ Vb,
                                                  u16* __restrict__ attnT) {
  __shared__ __align__(16) u16 Plds[4][2048];  // 4KB per wave, XOR-swizzled
  int bh = blockIdx.y;
  int b = bh >> 3, h = bh & 7;
  int tid = threadIdx.x, w = tid >> 6, lane = tid & 63;
  int q4 = lane >> 4, lr = lane & 15;
  char* Pb = (char*)(&Plds[w][0]);
  const u16* Qh = Qb + (size_t)bh * 1024 * 64;
  const u16* Kh = Kb + (size_t)bh * 1024 * 64;
  const u16* Vh = Vb + (size_t)bh * 64 * 1024;
  int n_base = blockIdx.x * 128 + w * 32;

  short8 qf[2][2];
#pragma unroll
  for (int r = 0; r < 2; ++r)
#pragma unroll
    for (int ks = 0; ks < 2; ++ks)
      qf[r][ks] = *(const short8*)&Qh[(size_t)(n_base + r * 16 + lr) * 64 +
                                      ks * 32 + q4 * 8];

  f32x4 O[2][4] = {};
  float mr[2][4], lsum[2][4];
#pragma unroll
  for (int r = 0; r < 2; ++r)
#pragma unroll
    for (int e = 0; e < 4; ++e) {
      mr[r][e] = -1e30f;
      lsum[r][e] = 0.f;
    }

  for (int kb = 0; kb < 16; ++kb) {
    int mm0 = kb * 64;
    f32x4 S[2][4] = {};
    short8 kf[4][2];
#pragma unroll
    for (int j = 0; j < 4; ++j)
#pragma unroll
      for (int ks = 0; ks < 2; ++ks)
        kf[j][ks] = *(const short8*)&Kh[(size_t)(mm0 + j * 16 + lr) * 64 +
                                        ks * 32 + q4 * 8];
#pragma unroll
    for (int r = 0; r < 2; ++r)
#pragma unroll
      for (int j = 0; j < 4; ++j) {
        S[r][j] = __builtin_amdgcn_mfma_f32_16x16x32_bf16(qf[r][0], kf[j][0],
                                                          S[r][j], 0, 0, 0);
        S[r][j] = __builtin_amdgcn_mfma_f32_16x16x32_bf16(qf[r][1], kf[j][1],
                                                          S[r][j], 0, 0, 0);
      }
    // ---- online softmax (rows live across 16-lane groups; butterfly reduce)
#pragma unroll
    for (int r = 0; r < 2; ++r)
#pragma unroll
      for (int e = 0; e < 4; ++e) {
        float mx = fmaxf(fmaxf(S[r][0][e], S[r][1][e]),
                         fmaxf(S[r][2][e], S[r][3][e]));
#pragma unroll
        for (int msk = 1; msk < 16; msk <<= 1)
          mx = fmaxf(mx, __shfl_xor(mx, msk, 64));
        float mnew = fmaxf(mr[r][e], mx);
        float alpha = __builtin_amdgcn_exp2f((mr[r][e] - mnew) * CS);
        mr[r][e] = mnew;
        float ps = 0.f;
#pragma unroll
        for (int j = 0; j < 4; ++j) {
          float p = __builtin_amdgcn_exp2f((S[r][j][e] - mnew) * CS);
          S[r][j][e] = p;
          ps += p;
        }
#pragma unroll
        for (int msk = 1; msk < 16; msk <<= 1) ps += __shfl_xor(ps, msk, 64);
        lsum[r][e] = lsum[r][e] * alpha + ps;
#pragma unroll
        for (int j = 0; j < 4; ++j) O[r][j][e] *= alpha;
      }
    // ---- P -> LDS (bf16, XOR swizzle to kill the 128B-stride conflict)
#pragma unroll
    for (int r = 0; r < 2; ++r)
#pragma unroll
      for (int j = 0; j < 4; ++j)
#pragma unroll
        for (int e = 0; e < 4; ++e) {
          int row = r * 16 + q4 * 4 + e;
          int col = j * 16 + lr;
          *(u16*)(Pb + row * 128 + ((col * 2) ^ ((row & 7) << 4))) =
              to_bf16(S[r][j][e]);
        }
    __syncthreads();
    // ---- PV
#pragma unroll
    for (int ks = 0; ks < 2; ++ks) {
      short8 pf[2], vf[4];
#pragma unroll
      for (int r = 0; r < 2; ++r) {
        int row = r * 16 + lr;
        pf[r] = *(const short8*)(Pb + row * 128 +
                                 ((ks * 64 + q4 * 16) ^ ((row & 7) << 4)));
      }
#pragma unroll
      for (int j = 0; j < 4; ++j)
        vf[j] = *(const short8*)&Vh[(size_t)(j * 16 + lr) * 1024 + mm0 +
                                    ks * 32 + q4 * 8];
#pragma unroll
      for (int r = 0; r < 2; ++r)
#pragma unroll
        for (int j = 0; j < 4; ++j)
          O[r][j] = __builtin_amdgcn_mfma_f32_16x16x32_bf16(pf[r], vf[j],
                                                            O[r][j], 0, 0, 0);
    }
    __syncthreads();
  }
  // ---- normalize + store attnT[b][n][h*64 + c]
#pragma unroll
  for (int r = 0; r < 2; ++r)
#pragma unroll
    for (int e = 0; e < 4; ++e) {
      float rl = 1.0f / lsum[r][e];
      int n = n_base + r * 16 + q4 * 4 + e;
#pragma unroll
      for (int j = 0; j < 4; ++j)
        attnT[((size_t)b * 1024 + n) * 512 + h * 64 + j * 16 + lr] =
            to_bf16(O[r][j][e] * rl);
    }
}

// ---------------------------------------------------------------------------
extern "C" void kernel_launch(void* const* d_in, const int* in_sizes, int n_in,
                              void* d_out, int out_size, void* d_ws,
                              size_t ws_size, hipStream_t stream) {
  const float* x      = (const float*)d_in[0];  // (16,512,32,32)
  const float* qkv_w  = (const float*)d_in[1];  // (1536,512)
  const float* qkv_b  = (const float*)d_in[2];  // (1536,)
  const float* out_w  = (const float*)d_in[3];  // (512,512)
  const float* out_b  = (const float*)d_in[4];  // (512,)
  const float* gamma  = (const float*)d_in[5];  // (1,)
  float* out = (float*)d_out;

  u16* xT  = (u16*)d_ws;          // [16][1024][512]
  u16* Qb  = xT + 8388608;        // [128][1024][64]
  u16* Kbf = Qb + 8388608;        // [128][1024][64]
  u16* Vbf = Kbf + 8388608;       // [128][64][1024]
  u16* aT  = Vbf + 8388608;       // [16][1024][512]
  u16* wq  = aT + 8388608;        // qkv_w bf16 (1536*512)
  u16* wo  = wq + 786432;         // out_w bf16 (512*512)

  // 1) convert / transpose inputs to bf16
  xpose_cvt<<<dim3(32, 16, 16), 256, 0, stream>>>(x, xT);
  cvt_bf16<<<3072, 256, 0, stream>>>(qkv_w, wq, 786432);
  cvt_bf16<<<1024, 256, 0, stream>>>(out_w, wo, 262144);

  // 2) QKV projection. Q,K via transposed orientation (rows=n, cols=o<1024)
  gemm_bt<0><<<dim3(8, 8, 16), 256, 0, stream>>>(
      xT, wq, (long)524288, (long)0, qkv_b, nullptr, nullptr, Qb, Kbf, nullptr,
      nullptr);
  // 3) V via normal orientation (rows=o' in [0,512), cols=n)
  gemm_bt<1><<<dim3(8, 4, 16), 256, 0, stream>>>(
      wq + 524288, xT, (long)0, (long)524288, qkv_b + 1024, nullptr, nullptr,
      nullptr, nullptr, Vbf, nullptr);

  // 4) fused flash attention -> attnT[b][n][512]
  attn_fused<<<dim3(8, 128, 1), 256, 0, stream>>>(Qb, Kbf, Vbf, aT);

  // 5) output projection + bias + gamma*out + x  -> fp32 d_out
  gemm_bt<2><<<dim3(8, 4, 16), 256, 0, stream>>>(
      wo, aT, (long)0, (long)524288, out_b, x, gamma, nullptr, nullptr, nullptr,
      out);
}

// Round 2
// 206.561 us; speedup vs baseline: 1.1907x; 1.1907x over previous
//
#include <hip/hip_runtime.h>
#include <stdint.h>

typedef unsigned short u16;
typedef __attribute__((ext_vector_type(8))) short short8;
typedef __attribute__((ext_vector_type(4))) float f32x4;
typedef __attribute__((ext_vector_type(2))) unsigned uint2v;

#define AS1C(p) ((const __attribute__((address_space(1))) void*)(p))
#define AS3(p)  ((__attribute__((address_space(3))) void*)(p))

__device__ __forceinline__ u16 to_bf16(float f) {
  unsigned u = __builtin_bit_cast(unsigned, f);
  u += 0x7FFFu + ((u >> 16) & 1u);
  return (u16)(u >> 16);
}

// ---------------------------------------------------------------------------
// x[b][c][n] fp32 -> xT[b][n][c] bf16   (B=16, C=512, N=1024)
__global__ __launch_bounds__(256) void xpose_cvt(const float* __restrict__ x,
                                                 u16* __restrict__ xT) {
  __shared__ float t[32][33];
  int b = blockIdx.z;
  int n0 = blockIdx.x * 32, c0 = blockIdx.y * 32;
  int tx = threadIdx.x & 31, ty = threadIdx.x >> 5;  // ty 0..7
  const float* xp = x + (size_t)b * 512 * 1024;
#pragma unroll
  for (int i = 0; i < 32; i += 8)
    t[ty + i][tx] = xp[(size_t)(c0 + ty + i) * 1024 + n0 + tx];
  __syncthreads();
  u16* op = xT + (size_t)b * 1024 * 512;
#pragma unroll
  for (int i = 0; i < 32; i += 8)
    op[(size_t)(n0 + ty + i) * 512 + c0 + tx] = to_bf16(t[tx][ty + i]);
}

__global__ __launch_bounds__(256) void cvt_bf16(const float* __restrict__ s,
                                                u16* __restrict__ d, int n) {
  int i = blockIdx.x * 256 + threadIdx.x;
  if (i < n) d[i] = to_bf16(s[i]);
}

// ---------------------------------------------------------------------------
// Generic 128x128-tile bf16 GEMM, K=512, BK=32 (m97 structure, unchanged).
template <int MODE>
__global__ __launch_bounds__(256) void gemm_bt(
    const u16* __restrict__ Abase, const u16* __restrict__ Bbase,
    long saB, long sbB,
    const float* __restrict__ bias, const float* __restrict__ xres,
    const float* __restrict__ gammap,
    u16* __restrict__ oq, u16* __restrict__ ok, u16* __restrict__ ov,
    float* __restrict__ of) {
  __shared__ __align__(16) u16 lsA[128 * 32];
  __shared__ __align__(16) u16 lsB[128 * 32];
  int b = blockIdx.z;
  const u16* Ag = Abase + (size_t)b * saB;
  const u16* Bg = Bbase + (size_t)b * sbB;
  int m0 = blockIdx.y * 128, n0 = blockIdx.x * 128;
  int tid = threadIdx.x;
  int w = tid >> 6, l = tid & 63;
  int wr = w >> 1, wc = w & 1;
  int lq = l >> 4, lr = l & 15;
  int rowA = w * 32 + (l >> 2);
  int k8 = (l & 3) * 8;
  f32x4 acc[4][4] = {};
  for (int kk = 0; kk < 16; ++kk) {
    int ko = kk * 32;
    __builtin_amdgcn_global_load_lds(
        AS1C(Ag + (size_t)(m0 + rowA) * 512 + ko + k8),
        AS3(&lsA[rowA * 32 + k8]), 16, 0, 0);
    __builtin_amdgcn_global_load_lds(
        AS1C(Ag + (size_t)(m0 + rowA + 16) * 512 + ko + k8),
        AS3(&lsA[(rowA + 16) * 32 + k8]), 16, 0, 0);
    __builtin_amdgcn_global_load_lds(
        AS1C(Bg + (size_t)(n0 + rowA) * 512 + ko + k8),
        AS3(&lsB[rowA * 32 + k8]), 16, 0, 0);
    __builtin_amdgcn_global_load_lds(
        AS1C(Bg + (size_t)(n0 + rowA + 16) * 512 + ko + k8),
        AS3(&lsB[(rowA + 16) * 32 + k8]), 16, 0, 0);
    __syncthreads();
    short8 af[4], bfr[4];
#pragma unroll
    for (int m = 0; m < 4; ++m)
      af[m] = *(const short8*)&lsA[(wr * 64 + m * 16 + lr) * 32 + lq * 8];
#pragma unroll
    for (int j = 0; j < 4; ++j)
      bfr[j] = *(const short8*)&lsB[(wc * 64 + j * 16 + lr) * 32 + lq * 8];
#pragma unroll
    for (int m = 0; m < 4; ++m)
#pragma unroll
      for (int j = 0; j < 4; ++j)
        acc[m][j] = __builtin_amdgcn_mfma_f32_16x16x32_bf16(af[m], bfr[j],
                                                            acc[m][j], 0, 0, 0);
    __syncthreads();
  }
  float g = (MODE == 2) ? gammap[0] : 0.f;
#pragma unroll
  for (int m = 0; m < 4; ++m)
#pragma unroll
    for (int j = 0; j < 4; ++j)
#pragma unroll
      for (int e = 0; e < 4; ++e) {
        int row = m0 + wr * 64 + m * 16 + lq * 4 + e;
        int col = n0 + wc * 64 + j * 16 + lr;
        float v = acc[m][j][e];
        if (MODE == 0) {
          int o = col, n = row;
          v += bias[o];
          int oo = (o < 512) ? o : o - 512;
          int hh = oo >> 6, cc = oo & 63;
          u16* dst = (o < 512) ? oq : ok;
          dst[((size_t)(b * 8 + hh) * 1024 + n) * 64 + cc] = to_bf16(v);
        } else if (MODE == 1) {
          int o = row, n = col;
          v += bias[o];  // bias pre-offset by +1024 on host side
          int hh = o >> 6, cc = o & 63;
          ov[((size_t)(b * 8 + hh) * 64 + cc) * 1024 + n] = to_bf16(v);
        } else {
          int o = row, n = col;
          v += bias[o];
          size_t idx = ((size_t)b * 512 + o) * 1024 + n;
          of[idx] = g * v + xres[idx];
        }
      }
}

// ---------------------------------------------------------------------------
// Flash attention, barrier-free. Q/K in [bh][n][64] bf16, V in [bh][c][n].
// 4 waves x 32 q-rows; KBLK=64. Swapped QK^T: S=mfma(K,Q) so lane (q=lane&15)
// holds 16 k-values per r -> in-lane softmax + 2 shuffles. P bounced through
// wave-PRIVATE LDS (no __syncthreads anywhere). Defer-max rescale (T13).
#define CS 0.18033688f  // (1/sqrt(64)) * log2(e)

__global__ __launch_bounds__(256) void attn_fused(const u16* __restrict__ Qb,
                                                  const u16* __restrict__ Kb,
                                                  const u16* __restrict__ Vb,
                                                  u16* __restrict__ attnT) {
  __shared__ __align__(16) u16 Plds[4][2048];  // 4KB per wave, XOR-swizzled
  int L = blockIdx.x;
  // XCD-bijective swizzle: all 8 n-blocks of a bh land on one XCD (L2 reuse)
  int bh = (L & 7) | ((L >> 6) << 3);
  int nb = (L >> 3) & 7;
  int b = bh >> 3, h = bh & 7;
  int tid = threadIdx.x, w = tid >> 6, lane = tid & 63;
  int g = lane >> 4, lr = lane & 15;
  char* Pb = (char*)(&Plds[w][0]);
  const u16* Qh = Qb + (size_t)bh * 65536;
  const u16* Kh = Kb + (size_t)bh * 65536;
  const u16* Vh = Vb + (size_t)bh * 65536;
  int n_base = nb * 128 + w * 32;
  int sz = (lr & 7) << 4;  // XOR swizzle for this lane's P rows (q&7 == lr&7)

  short8 qf[2][2];
#pragma unroll
  for (int r = 0; r < 2; ++r)
#pragma unroll
    for (int ks = 0; ks < 2; ++ks)
      qf[r][ks] = *(const short8*)&Qh[(size_t)(n_base + r * 16 + lr) * 64 +
                                      ks * 32 + g * 8];

  f32x4 O[2][4] = {};
  float mrr[2] = {-1e30f, -1e30f};
  float mcs[2] = {-1e30f, -1e30f};
  float lsum[2] = {0.f, 0.f};

  short8 kf[4][2];
#pragma unroll
  for (int j = 0; j < 4; ++j)
#pragma unroll
    for (int ks = 0; ks < 2; ++ks)
      kf[j][ks] = *(const short8*)&Kh[(size_t)(j * 16 + lr) * 64 + ks * 32 + g * 8];

  for (int kb = 0; kb < 16; ++kb) {
    int mm0 = kb * 64;
    // ---- S = K x Q^T : D-row = k (j*16 + g*4 + e), D-col = q (r*16 + lr)
    f32x4 S[4][2] = {};
#pragma unroll
    for (int j = 0; j < 4; ++j)
#pragma unroll
      for (int r = 0; r < 2; ++r) {
        S[j][r] = __builtin_amdgcn_mfma_f32_16x16x32_bf16(kf[j][0], qf[r][0],
                                                          S[j][r], 0, 0, 0);
        S[j][r] = __builtin_amdgcn_mfma_f32_16x16x32_bf16(kf[j][1], qf[r][1],
                                                          S[j][r], 0, 0, 0);
      }
    // ---- V loads issued early: latency hides under softmax VALU
    short8 vf[4][2];
#pragma unroll
    for (int jc = 0; jc < 4; ++jc)
#pragma unroll
      for (int ks = 0; ks < 2; ++ks)
        vf[jc][ks] = *(const short8*)&Vh[(size_t)(jc * 16 + lr) * 1024 + mm0 +
                                         ks * 32 + g * 8];
    // ---- row max: 16 in-lane values + 2 cross-group shuffles
    float mx[2];
#pragma unroll
    for (int r = 0; r < 2; ++r) {
      float m0 = fmaxf(fmaxf(S[0][r][0], S[0][r][1]), fmaxf(S[0][r][2], S[0][r][3]));
      float m1 = fmaxf(fmaxf(S[1][r][0], S[1][r][1]), fmaxf(S[1][r][2], S[1][r][3]));
      float m2 = fmaxf(fmaxf(S[2][r][0], S[2][r][1]), fmaxf(S[2][r][2], S[2][r][3]));
      float m3 = fmaxf(fmaxf(S[3][r][0], S[3][r][1]), fmaxf(S[3][r][2], S[3][r][3]));
      float m = fmaxf(fmaxf(m0, m1), fmaxf(m2, m3));
      m = fmaxf(m, __shfl_xor(m, 16, 64));
      m = fmaxf(m, __shfl_xor(m, 32, 64));
      mx[r] = m;
    }
    // ---- defer-max: rescale only when max grew enough to matter
    bool need = (mx[0] > mrr[0] + 60.f) || (mx[1] > mrr[1] + 60.f);
    if (__any(need)) {
#pragma unroll
      for (int r = 0; r < 2; ++r) {
        float mnew = fmaxf(mrr[r], mx[r]);
        float al = __builtin_amdgcn_exp2f((mrr[r] - mnew) * CS);
        mrr[r] = mnew;
        mcs[r] = mnew * CS;
        lsum[r] *= al;
        float alE[4];
#pragma unroll
        for (int e = 0; e < 4; ++e)
          alE[e] = __shfl(al, (lane & 48) | (g * 4 + e), 64);
#pragma unroll
        for (int jc = 0; jc < 4; ++jc)
#pragma unroll
          for (int e = 0; e < 4; ++e) O[r][jc][e] *= alE[e];
      }
    }
    // ---- P = exp2(S*CS - m*CS), pack pairs, 8x ds_write_b64
#pragma unroll
    for (int r = 0; r < 2; ++r) {
      int rowoff = (r * 16 + lr) * 128;
      float p_s = 0.f;
#pragma unroll
      for (int j = 0; j < 4; ++j) {
        float p0 = __builtin_amdgcn_exp2f(S[j][r][0] * CS - mcs[r]);
        float p1 = __builtin_amdgcn_exp2f(S[j][r][1] * CS - mcs[r]);
        float p2 = __builtin_amdgcn_exp2f(S[j][r][2] * CS - mcs[r]);
        float p3 = __builtin_amdgcn_exp2f(S[j][r][3] * CS - mcs[r]);
        p_s += (p0 + p1) + (p2 + p3);
        unsigned w0, w1;
        asm("v_cvt_pk_bf16_f32 %0, %1, %2" : "=v"(w0) : "v"(p0), "v"(p1));
        asm("v_cvt_pk_bf16_f32 %0, %1, %2" : "=v"(w1) : "v"(p2), "v"(p3));
        *(uint2v*)(Pb + rowoff + ((j * 32 + g * 8) ^ sz)) = (uint2v){w0, w1};
      }
      p_s += __shfl_xor(p_s, 16, 64);
      p_s += __shfl_xor(p_s, 32, 64);
      lsum[r] += p_s;
    }
    // ---- K prefetch for next kb: latency hides under PV MFMAs
    int mm1 = ((kb + 1) & 15) * 64;
#pragma unroll
    for (int j = 0; j < 4; ++j)
#pragma unroll
      for (int ks = 0; ks < 2; ++ks)
        kf[j][ks] = *(const short8*)&Kh[(size_t)(mm1 + j * 16 + lr) * 64 +
                                        ks * 32 + g * 8];
    // ---- PV: O[q][c] += P x V  (no barrier: P buffer is wave-private)
    short8 pf[2][2];
#pragma unroll
    for (int r = 0; r < 2; ++r) {
      int rowoff = (r * 16 + lr) * 128;
#pragma unroll
      for (int ks = 0; ks < 2; ++ks)
        pf[r][ks] = *(const short8*)(Pb + rowoff + ((ks * 64 + g * 16) ^ sz));
    }
#pragma unroll
    for (int r = 0; r < 2; ++r)
#pragma unroll
      for (int jc = 0; jc < 4; ++jc) {
        O[r][jc] = __builtin_amdgcn_mfma_f32_16x16x32_bf16(pf[r][0], vf[jc][0],
                                                           O[r][jc], 0, 0, 0);
        O[r][jc] = __builtin_amdgcn_mfma_f32_16x16x32_bf16(pf[r][1], vf[jc][1],
                                                           O[r][jc], 0, 0, 0);
      }
  }
  // ---- normalize + store attnT[b][n][h*64 + c] (O-row q = r*16 + g*4 + e)
#pragma unroll
  for (int r = 0; r < 2; ++r) {
    float rl = 1.0f / lsum[r];
    float rlE[4];
#pragma unroll
    for (int e = 0; e < 4; ++e)
      rlE[e] = __shfl(rl, (lane & 48) | (g * 4 + e), 64);
#pragma unroll
    for (int e = 0; e < 4; ++e) {
      int n = n_base + r * 16 + g * 4 + e;
#pragma unroll
      for (int jc = 0; jc < 4; ++jc)
        attnT[((size_t)b * 1024 + n) * 512 + h * 64 + jc * 16 + lr] =
            to_bf16(O[r][jc][e] * rlE[e]);
    }
  }
}

// ---------------------------------------------------------------------------
extern "C" void kernel_launch(void* const* d_in, const int* in_sizes, int n_in,
                              void* d_out, int out_size, void* d_ws,
                              size_t ws_size, hipStream_t stream) {
  const float* x      = (const float*)d_in[0];  // (16,512,32,32)
  const float* qkv_w  = (const float*)d_in[1];  // (1536,512)
  const float* qkv_b  = (const float*)d_in[2];  // (1536,)
  const float* out_w  = (const float*)d_in[3];  // (512,512)
  const float* out_b  = (const float*)d_in[4];  // (512,)
  const float* gamma  = (const float*)d_in[5];  // (1,)
  float* out = (float*)d_out;

  u16* xT  = (u16*)d_ws;          // [16][1024][512]
  u16* Qb  = xT + 8388608;        // [128][1024][64]
  u16* Kbf = Qb + 8388608;        // [128][1024][64]
  u16* Vbf = Kbf + 8388608;       // [128][64][1024]
  u16* aT  = Vbf + 8388608;       // [16][1024][512]
  u16* wq  = aT + 8388608;        // qkv_w bf16 (1536*512)
  u16* wo  = wq + 786432;         // out_w bf16 (512*512)

  // 1) convert / transpose inputs to bf16
  xpose_cvt<<<dim3(32, 16, 16), 256, 0, stream>>>(x, xT);
  cvt_bf16<<<3072, 256, 0, stream>>>(qkv_w, wq, 786432);
  cvt_bf16<<<1024, 256, 0, stream>>>(out_w, wo, 262144);

  // 2) QKV projection. Q,K via transposed orientation (rows=n, cols=o<1024)
  gemm_bt<0><<<dim3(8, 8, 16), 256, 0, stream>>>(
      xT, wq, (long)524288, (long)0, qkv_b, nullptr, nullptr, Qb, Kbf, nullptr,
      nullptr);
  // 3) V via normal orientation (rows=o' in [0,512), cols=n)
  gemm_bt<1><<<dim3(8, 4, 16), 256, 0, stream>>>(
      wq + 524288, xT, (long)0, (long)524288, qkv_b + 1024, nullptr, nullptr,
      nullptr, nullptr, Vbf, nullptr);

  // 4) fused flash attention -> attnT[b][n][512]  (barrier-free)
  attn_fused<<<1024, 256, 0, stream>>>(Qb, Kbf, Vbf, aT);

  // 5) output projection + bias + gamma*out + x  -> fp32 d_out
  gemm_bt<2><<<dim3(8, 4, 16), 256, 0, stream>>>(
      wo, aT, (long)0, (long)524288, out_b, x, gamma, nullptr, nullptr, nullptr,
      out);
}